// Round 1
// baseline (210.127 us; speedup 1.0000x reference)
//
#include <hip/hip_runtime.h>
#include <cmath>

#define A_CNT 196416
#define C_CNT 90
#define TOPK 100u

// ws layout (bytes):
//   [0, 785664)            keys[A]  (uint32 monotonic score keys)
//   [785664, 1047808)      hist1[65536]
//   [1047808, 1309952)     hist2[65536]
//   [1309952, 1310016)     ctrl[16]: 0=binB 1=G 2=T 3=n_gt 4=need_eq 5=cand_cnt 6=eq_cnt
//   [1310016, 1310528)     cand[128]
//   [1310528, 1314624)     eq[1024]
#define OFF_HIST1 785664u
#define OFF_HIST2 1047808u
#define OFF_CTRL  1309952u
#define OFF_CAND  1310016u
#define OFF_EQ    1310528u
#define WS_END    1314624u

// Kernel 1: wave-per-anchor max over 90 logits -> score key + coarse histogram.
// prob in (0.05, 1) => float bits in [0x3D4CCCCE, 0x3F800000] => top16 bins
// in [0x3D4C, 0x3F80]: 565 reachable bins, LDS-aggregated.
__global__ __launch_bounds__(256) void k_reduce(const float* __restrict__ cls,
                                                unsigned* __restrict__ keys,
                                                unsigned* __restrict__ hist1) {
    __shared__ unsigned lhist[576];
    for (int j = threadIdx.x; j < 576; j += 256) lhist[j] = 0u;
    __syncthreads();
    const int lane = threadIdx.x & 63;
    const int wid  = (blockIdx.x << 2) + (threadIdx.x >> 6);
    const int nw   = gridDim.x << 2;
    for (int a = wid; a < A_CNT; a += nw) {
        const float* row = cls + (size_t)a * C_CNT;
        float v = -INFINITY;
        int vi = 1 << 20;
        if (lane < 45) {  // 45 lanes * float2 = 90 elems; 8B-aligned (a*360 % 8 == 0)
            float2 p = *(const float2*)(row + 2 * lane);
            v = p.x; vi = 2 * lane;
            if (p.y > v) { v = p.y; vi = 2 * lane + 1; }  // strict > keeps first index
        }
#pragma unroll
        for (int off = 32; off > 0; off >>= 1) {
            float ov = __shfl_xor(v, off);
            int   oi = __shfl_xor(vi, off);
            if (ov > v || (ov == v && oi < vi)) { v = ov; vi = oi; }
        }
        if (lane == 0) {
            float prob = 1.0f / (1.0f + expf(-v));   // sigmoid of max == max of sigmoids
            unsigned key = (prob > 0.05f) ? __float_as_uint(prob) : 0u;
            keys[a] = key;
            if (key == 0u) {
                atomicAdd(&hist1[0], 1u);            // thresholded-out (rare/never here)
            } else {
                unsigned bin = key >> 16;
                if (bin > 0x3F80u) bin = 0x3F80u;    // prob==1.0 paranoia
                atomicAdd(&lhist[bin - 0x3D4Cu], 1u);
            }
        }
    }
    __syncthreads();
    for (int j = threadIdx.x; j < 576; j += 256) {
        unsigned c = lhist[j];
        if (c) atomicAdd(&hist1[0x3D4Cu + j], c);
    }
}

// Two-level parallel suffix-scan select over a 65536-bin histogram.
// mode 0: hist1 -> ctrl[0]=binB (top16 bits at rank 100), ctrl[1]=G (# strictly above binB)
// mode 1: hist2 (low16 among binB) -> ctrl[2]=T (exact 32-bit key threshold),
//         ctrl[3]=n_gt (# keys > T, < 100), ctrl[4]=need_eq (# ties to take)
__global__ __launch_bounds__(256) void k_scan(const unsigned* __restrict__ hist,
                                              unsigned* __restrict__ ctrl, int mode) {
    __shared__ unsigned sdata[256];
    __shared__ unsigned sbin[2];
    const int t = threadIdx.x;
    const unsigned target = TOPK;
    const unsigned above0 = (mode == 0) ? 0u : ctrl[1];

    // level 1: per-thread chunk sums (256 bins each)
    unsigned s = 0;
    const unsigned* hrow = hist + t * 256;
#pragma unroll 8
    for (int j = 0; j < 256; ++j) s += hrow[j];
    sdata[t] = s;
    for (int d = 1; d < 256; d <<= 1) {       // Hillis-Steele inclusive suffix scan
        __syncthreads();
        unsigned add = (t + d < 256) ? sdata[t + d] : 0u;
        __syncthreads();
        sdata[t] += add;
    }
    __syncthreads();
    {
        unsigned mysuf  = sdata[t] + above0;
        unsigned nxtsuf = ((t < 255) ? sdata[t + 1] : 0u) + above0;
        if (nxtsuf < target && mysuf >= target) { sbin[0] = (unsigned)t; sbin[1] = nxtsuf; }
    }
    __syncthreads();
    const unsigned chunkB = sbin[0];
    const unsigned gAbove = sbin[1];

    // level 2: exact bin within the crossing chunk
    unsigned v = hist[chunkB * 256 + t];
    sdata[t] = v;
    for (int d = 1; d < 256; d <<= 1) {
        __syncthreads();
        unsigned add = (t + d < 256) ? sdata[t + d] : 0u;
        __syncthreads();
        sdata[t] += add;
    }
    __syncthreads();
    {
        unsigned mysuf  = sdata[t] + gAbove;
        unsigned nxtsuf = ((t < 255) ? sdata[t + 1] : 0u) + gAbove;
        if (nxtsuf < target && mysuf >= target) {
            unsigned bin = chunkB * 256 + (unsigned)t;
            if (mode == 0) { ctrl[0] = bin; ctrl[1] = nxtsuf; }
            else {
                ctrl[2] = (ctrl[0] << 16) | bin;
                ctrl[3] = nxtsuf;
                ctrl[4] = target - nxtsuf;
            }
        }
    }
}

__global__ __launch_bounds__(256) void k_hist2(const unsigned* __restrict__ keys,
                                               const unsigned* __restrict__ ctrl,
                                               unsigned* __restrict__ hist2) {
    const unsigned binB = ctrl[0];
    int i = blockIdx.x * 256 + threadIdx.x;
    const int n = gridDim.x * 256;
    for (; i < A_CNT; i += n) {
        unsigned k = keys[i];
        if ((k >> 16) == binB) atomicAdd(&hist2[k & 0xFFFFu], 1u);
    }
}

__global__ __launch_bounds__(256) void k_gather(const unsigned* __restrict__ keys,
                                                unsigned* __restrict__ ctrl,
                                                unsigned* __restrict__ cand,
                                                unsigned* __restrict__ eqi) {
    const unsigned T = ctrl[2];
    int i = blockIdx.x * 256 + threadIdx.x;
    const int n = gridDim.x * 256;
    for (; i < A_CNT; i += n) {
        unsigned k = keys[i];
        if (k > T) {
            unsigned p = atomicAdd(&ctrl[5], 1u);
            if (p < 128u) cand[p] = (unsigned)i;
        } else if (k == T) {
            unsigned p = atomicAdd(&ctrl[6], 1u);
            if (p < 1024u) eqi[p] = (unsigned)i;
        }
    }
}

// Final: rank 100 winners (key desc, idx asc — lax.top_k stable order),
// recompute per-class sigmoid argmax (first-index tie like jnp.argmax),
// decode + clip boxes, write [boxes(400) | scores(100) | classes(100)] as f32.
__global__ __launch_bounds__(128) void k_final(const float* __restrict__ cls,
                                               const float* __restrict__ reg,
                                               const float* __restrict__ anc,
                                               const unsigned* __restrict__ ctrl,
                                               const unsigned* __restrict__ cand,
                                               const unsigned* __restrict__ eqi,
                                               const unsigned* __restrict__ keys,
                                               float* __restrict__ out) {
    __shared__ unsigned sel[TOPK];
    const int t = threadIdx.x;
    const unsigned n_gt = ctrl[3];
    const unsigned need_eq = ctrl[4];
    unsigned eq_cnt = ctrl[6];
    if (eq_cnt > 1024u) eq_cnt = 1024u;

    if (t < (int)n_gt) {  // rank strictly-greater candidates
        unsigned mi = cand[t], mk = keys[mi], r = 0;
        for (unsigned j = 0; j < n_gt; ++j) {
            unsigned oj = cand[j], ok = keys[oj];
            if (ok > mk || (ok == mk && oj < mi)) r++;
        }
        sel[r] = mi;
    }
    for (unsigned e = (unsigned)t; e < eq_cnt; e += 128u) {  // ties: smallest index first
        unsigned mi = eqi[e], r = 0;
        for (unsigned j = 0; j < eq_cnt; ++j)
            if (eqi[j] < mi) r++;
        if (r < need_eq) sel[n_gt + r] = mi;
    }
    __syncthreads();

    if (t < (int)TOPK) {
        const unsigned a = sel[t];
        const float* row = cls + (size_t)a * C_CNT;
        float bp = -1.0f; int bi = 0;
        for (int c = 0; c < C_CNT; ++c) {
            float p = 1.0f / (1.0f + expf(-row[c]));
            if (p > bp) { bp = p; bi = c; }   // strict > == first-index tie-break
        }
        float score = (keys[a] == 0u) ? 0.0f : bp;  // thresholded semantics
        float x1a = anc[a * 4 + 0], y1a = anc[a * 4 + 1];
        float x2a = anc[a * 4 + 2], y2a = anc[a * 4 + 3];
        float wa = x2a - x1a, ha = y2a - y1a;
        float cxa = x1a + 0.5f * wa, cya = y1a + 0.5f * ha;
        float dx = reg[a * 4 + 0] * 0.1f, dy = reg[a * 4 + 1] * 0.1f;
        float dw = reg[a * 4 + 2] * 0.2f, dh = reg[a * 4 + 3] * 0.2f;
        float cx = cxa + dx * wa, cy = cya + dy * ha;
        float w = expf(dw) * wa, h = expf(dh) * ha;
        out[t * 4 + 0] = fmaxf(cx - 0.5f * w, 0.0f);
        out[t * 4 + 1] = fmaxf(cy - 0.5f * h, 0.0f);
        out[t * 4 + 2] = fminf(cx + 0.5f * w, 1024.0f);
        out[t * 4 + 3] = fminf(cy + 0.5f * h, 1024.0f);
        out[400 + t] = score;
        out[500 + t] = (float)bi;
    }
}

extern "C" void kernel_launch(void* const* d_in, const int* in_sizes, int n_in,
                              void* d_out, int out_size, void* d_ws, size_t ws_size,
                              hipStream_t stream) {
    const float* reg = (const float*)d_in[1];
    const float* cls = (const float*)d_in[2];
    const float* anc = (const float*)d_in[3];
    float* out = (float*)d_out;
    char* ws = (char*)d_ws;
    unsigned* keys  = (unsigned*)ws;
    unsigned* hist1 = (unsigned*)(ws + OFF_HIST1);
    unsigned* hist2 = (unsigned*)(ws + OFF_HIST2);
    unsigned* ctrl  = (unsigned*)(ws + OFF_CTRL);
    unsigned* cand  = (unsigned*)(ws + OFF_CAND);
    unsigned* eqi   = (unsigned*)(ws + OFF_EQ);

    hipMemsetAsync(ws + OFF_HIST1, 0, WS_END - OFF_HIST1, stream);
    k_reduce<<<1024, 256, 0, stream>>>(cls, keys, hist1);
    k_scan<<<1, 256, 0, stream>>>(hist1, ctrl, 0);
    k_hist2<<<256, 256, 0, stream>>>(keys, ctrl, hist2);
    k_scan<<<1, 256, 0, stream>>>(hist2, ctrl, 1);
    k_gather<<<256, 256, 0, stream>>>(keys, ctrl, cand, eqi);
    k_final<<<1, 128, 0, stream>>>(cls, reg, anc, ctrl, cand, eqi, keys, out);
}

// Round 2
// 165.113 us; speedup vs baseline: 1.2726x; 1.2726x over previous
//
#include <hip/hip_runtime.h>
#include <cmath>

#define A_CNT 196416
#define C_CNT 90
#define TOT_ELEMS (A_CNT * C_CNT)   // 17677440
#define TOPK 100u
#define AB 128                       // anchors per reduce block
#define NB_REDUCE ((A_CNT + AB - 1) / AB)   // 1535

// ws layout (bytes):
//   [0, 785664)            keys[A]  (uint32 monotonic score keys; 0 = below threshold)
//   [785664, 789760)       hist1[1024]  (coarse: idx 0 = zero-key, 1..565 = top16-0x3D4B)
//   [789760, 1051904)      hist2[65536] (low 16 bits within binB)
//   [1051904, 1051968)     ctrl[16]: 0=binB(top16) 1=G 2=T 3=n_gt 4=need_eq 5=cand_cnt 6=eq_cnt
//   [1051968, 1052480)     cand[128]
//   [1052480, 1056576)     eq[1024]
#define OFF_HIST1 785664u
#define OFF_HIST2 789760u
#define OFF_CTRL  1051904u
#define OFF_CAND  1051968u
#define OFF_EQ    1052480u
#define WS_END    1056576u

// Kernel 1: LDS-staged, coalesced max-reduce over 90 logits per anchor.
// 128 anchors/block staged flat (46080 B) via float4; 2 threads/anchor reduce
// from LDS (48/42 split, float2 reads, 2-way bank aliasing = free).
__global__ __launch_bounds__(256) void k_reduce(const float* __restrict__ cls,
                                                unsigned* __restrict__ keys,
                                                unsigned* __restrict__ hist1) {
    __shared__ alignas(16) float smem[AB * C_CNT];   // 46080 B, flat (same layout as global)
    __shared__ unsigned lhist[1024];
    const int t = threadIdx.x;
    for (int j = t; j < 1024; j += 256) lhist[j] = 0u;

    const int base = blockIdx.x * (AB * C_CNT);
    const int nvc = min(AB * C_CNT, TOT_ELEMS - base) >> 2;   // valid float4 chunks
    const float4* __restrict__ g4 = (const float4*)(cls + base);
    float4* __restrict__ s4 = (float4*)smem;
    for (int c = t; c < nvc; c += 256) s4[c] = g4[c];         // coalesced, ~11 loads in flight
    __syncthreads();

    const int r = t >> 1;            // anchor within block
    const int h = t & 1;             // half: 0 -> cols [0,48), 1 -> cols [48,90)
    const int a = blockIdx.x * AB + r;
    float m = -INFINITY;
    if (a < A_CNT) {
        const float2* q = (const float2*)(smem + r * C_CNT + (h ? 48 : 0));
        const int n2 = h ? 21 : 24;
        for (int i = 0; i < n2; ++i) {
            float2 p = q[i];
            m = fmaxf(m, fmaxf(p.x, p.y));
        }
    }
    float om = __shfl_xor(m, 1);
    m = fmaxf(m, om);
    if (h == 0 && a < A_CNT) {
        float prob = 1.0f / (1.0f + expf(-m));      // sigmoid(max) == max(sigmoid)
        unsigned key = (prob > 0.05f) ? __float_as_uint(prob) : 0u;
        keys[a] = key;
        unsigned hidx = key ? (min(key >> 16, 0x3F80u) - 0x3D4Bu) : 0u;  // 0=zeros, 1..565
        atomicAdd(&lhist[hidx], 1u);
    }
    __syncthreads();
    for (int j = t; j < 1024; j += 256) {
        unsigned c = lhist[j];
        if (c) atomicAdd(&hist1[j], c);
    }
}

// Two-level suffix-scan select over NBINS = CHUNK*256 histogram bins.
// mode 0 (hist1, CHUNK=4):  ctrl[0]=binB top16 bits, ctrl[1]=G (# strictly above binB)
// mode 1 (hist2, CHUNK=256): ctrl[2]=T exact key, ctrl[3]=n_gt, ctrl[4]=need_eq
template <int CHUNK>
__global__ __launch_bounds__(256) void k_scan(const unsigned* __restrict__ hist,
                                              unsigned* __restrict__ ctrl, int mode) {
    __shared__ unsigned sdata[256];
    __shared__ unsigned sbin[2];
    const int t = threadIdx.x;
    const unsigned target = TOPK;
    const unsigned above0 = (mode == 0) ? 0u : ctrl[1];

    // level 1: per-thread chunk sums (uint4-vectorized)
    unsigned s = 0;
    const uint4* p = (const uint4*)(hist + t * CHUNK);
#pragma unroll 8
    for (int j = 0; j < CHUNK / 4; ++j) { uint4 u = p[j]; s += u.x + u.y + u.z + u.w; }
    sdata[t] = s;
    for (int d = 1; d < 256; d <<= 1) {     // Hillis-Steele inclusive suffix scan
        __syncthreads();
        unsigned add = (t + d < 256) ? sdata[t + d] : 0u;
        __syncthreads();
        sdata[t] += add;
    }
    __syncthreads();
    {
        unsigned mysuf  = sdata[t] + above0;
        unsigned nxtsuf = ((t < 255) ? sdata[t + 1] : 0u) + above0;
        if (nxtsuf < target && mysuf >= target) { sbin[0] = (unsigned)t; sbin[1] = nxtsuf - above0; }
    }
    __syncthreads();
    const unsigned chunkB = sbin[0];
    const unsigned gAbove = sbin[1] + above0;

    // level 2: exact bin within the crossing chunk
    unsigned v = (t < CHUNK) ? hist[chunkB * CHUNK + t] : 0u;
    sdata[t] = v;
    for (int d = 1; d < 256; d <<= 1) {
        __syncthreads();
        unsigned add = (t + d < 256) ? sdata[t + d] : 0u;
        __syncthreads();
        sdata[t] += add;
    }
    __syncthreads();
    {
        unsigned mysuf  = sdata[t] + gAbove;
        unsigned nxtsuf = ((t < 255) ? sdata[t + 1] : 0u) + gAbove;
        if (nxtsuf < target && mysuf >= target) {
            unsigned bin = chunkB * CHUNK + (unsigned)t;   // histogram index
            if (mode == 0) {
                ctrl[0] = bin ? (bin + 0x3D4Bu) : 0u;      // true top-16 bits
                ctrl[1] = nxtsuf;
            } else {
                ctrl[2] = (ctrl[0] << 16) | bin;
                ctrl[3] = nxtsuf;
                ctrl[4] = target - nxtsuf;
            }
        }
    }
}

__global__ __launch_bounds__(256) void k_hist2(const unsigned* __restrict__ keys,
                                               const unsigned* __restrict__ ctrl,
                                               unsigned* __restrict__ hist2) {
    const unsigned binB = ctrl[0];
    int i = blockIdx.x * 256 + threadIdx.x;
    const int n = gridDim.x * 256;
    for (; i < A_CNT; i += n) {
        unsigned k = keys[i];
        if ((k >> 16) == binB) atomicAdd(&hist2[k & 0xFFFFu], 1u);
    }
}

__global__ __launch_bounds__(256) void k_gather(const unsigned* __restrict__ keys,
                                                unsigned* __restrict__ ctrl,
                                                unsigned* __restrict__ cand,
                                                unsigned* __restrict__ eqi) {
    const unsigned T = ctrl[2];
    int i = blockIdx.x * 256 + threadIdx.x;
    const int n = gridDim.x * 256;
    for (; i < A_CNT; i += n) {
        unsigned k = keys[i];
        if (k > T) {
            unsigned p = atomicAdd(&ctrl[5], 1u);
            if (p < 128u) cand[p] = (unsigned)i;
        } else if (k == T) {
            unsigned p = atomicAdd(&ctrl[6], 1u);
            if (p < 1024u) eqi[p] = (unsigned)i;
        }
    }
}

// Final: rank 100 winners (key desc, idx asc — lax.top_k stable order),
// argmax over RAW logits (sigmoid monotonic; strict > = first-index tie like jnp.argmax),
// decode + clip boxes, write [boxes(400) | scores(100) | classes(100)] as f32.
__global__ __launch_bounds__(128) void k_final(const float* __restrict__ cls,
                                               const float* __restrict__ reg,
                                               const float* __restrict__ anc,
                                               const unsigned* __restrict__ ctrl,
                                               const unsigned* __restrict__ cand,
                                               const unsigned* __restrict__ eqi,
                                               const unsigned* __restrict__ keys,
                                               float* __restrict__ out) {
    __shared__ unsigned sel[TOPK];
    const int t = threadIdx.x;
    const unsigned n_gt = ctrl[3];
    const unsigned need_eq = ctrl[4];
    unsigned eq_cnt = ctrl[6];
    if (eq_cnt > 1024u) eq_cnt = 1024u;

    if (t < (int)n_gt) {  // rank strictly-greater candidates
        unsigned mi = cand[t], mk = keys[mi], r = 0;
        for (unsigned j = 0; j < n_gt; ++j) {
            unsigned oj = cand[j], ok = keys[oj];
            if (ok > mk || (ok == mk && oj < mi)) r++;
        }
        sel[r] = mi;
    }
    for (unsigned e = (unsigned)t; e < eq_cnt; e += 128u) {  // ties: smallest index first
        unsigned mi = eqi[e], r = 0;
        for (unsigned j = 0; j < eq_cnt; ++j)
            if (eqi[j] < mi) r++;
        if (r < need_eq) sel[n_gt + r] = mi;
    }
    __syncthreads();

    if (t < (int)TOPK) {
        const unsigned a = sel[t];
        const float* row = cls + (size_t)a * C_CNT;
        float bv = -INFINITY; int bi = 0;
        for (int c = 0; c < C_CNT; ++c) {
            float v = row[c];
            if (v > bv) { bv = v; bi = c; }
        }
        float score = __uint_as_float(keys[a]);   // prob bits, or 0.0 if thresholded
        float x1a = anc[a * 4 + 0], y1a = anc[a * 4 + 1];
        float x2a = anc[a * 4 + 2], y2a = anc[a * 4 + 3];
        float wa = x2a - x1a, ha = y2a - y1a;
        float cxa = x1a + 0.5f * wa, cya = y1a + 0.5f * ha;
        float dx = reg[a * 4 + 0] * 0.1f, dy = reg[a * 4 + 1] * 0.1f;
        float dw = reg[a * 4 + 2] * 0.2f, dh = reg[a * 4 + 3] * 0.2f;
        float cx = cxa + dx * wa, cy = cya + dy * ha;
        float w = expf(dw) * wa, h = expf(dh) * ha;
        out[t * 4 + 0] = fmaxf(cx - 0.5f * w, 0.0f);
        out[t * 4 + 1] = fmaxf(cy - 0.5f * h, 0.0f);
        out[t * 4 + 2] = fminf(cx + 0.5f * w, 1024.0f);
        out[t * 4 + 3] = fminf(cy + 0.5f * h, 1024.0f);
        out[400 + t] = score;
        out[500 + t] = (float)bi;
    }
}

extern "C" void kernel_launch(void* const* d_in, const int* in_sizes, int n_in,
                              void* d_out, int out_size, void* d_ws, size_t ws_size,
                              hipStream_t stream) {
    const float* reg = (const float*)d_in[1];
    const float* cls = (const float*)d_in[2];
    const float* anc = (const float*)d_in[3];
    float* out = (float*)d_out;
    char* ws = (char*)d_ws;
    unsigned* keys  = (unsigned*)ws;
    unsigned* hist1 = (unsigned*)(ws + OFF_HIST1);
    unsigned* hist2 = (unsigned*)(ws + OFF_HIST2);
    unsigned* ctrl  = (unsigned*)(ws + OFF_CTRL);
    unsigned* cand  = (unsigned*)(ws + OFF_CAND);
    unsigned* eqi   = (unsigned*)(ws + OFF_EQ);

    hipMemsetAsync(ws + OFF_HIST1, 0, WS_END - OFF_HIST1, stream);
    k_reduce<<<NB_REDUCE, 256, 0, stream>>>(cls, keys, hist1);
    k_scan<4><<<1, 256, 0, stream>>>(hist1, ctrl, 0);
    k_hist2<<<256, 256, 0, stream>>>(keys, ctrl, hist2);
    k_scan<256><<<1, 256, 0, stream>>>(hist2, ctrl, 1);
    k_gather<<<256, 256, 0, stream>>>(keys, ctrl, cand, eqi);
    k_final<<<1, 128, 0, stream>>>(cls, reg, anc, ctrl, cand, eqi, keys, out);
}